// Round 1
// baseline (6594.735 us; speedup 1.0000x reference)
//
#include <hip/hip_runtime.h>
#include <hip/hip_bf16.h>
#include <cstddef>

#define L_SEQ 2048
#define BATCH 2
#define HEADS 16
#define DMODEL 1024
#define DHEAD 64
#define ROWS (BATCH * L_SEQ)                    // 4096
#define X_ELEMS ((size_t)ROWS * DMODEL)         // 4194304 (x output elements)
#define ATT_OFF X_ELEMS                         // attention starts after x in d_out

// ---------- dtype-flexible load/store helpers ----------
template<bool BF>
__device__ __forceinline__ float ldin(const void* p, size_t i) {
    if constexpr (BF) return __bfloat162float(((const __hip_bfloat16*)p)[i]);
    else              return ((const float*)p)[i];
}
template<bool BF>
__device__ __forceinline__ void stout(void* p, size_t i, float v) {
    if constexpr (BF) ((__hip_bfloat16*)p)[i] = __float2bfloat16(v);
    else              ((float*)p)[i] = v;
}

// ---------- dtype detection: mask is all-ones by construction ----------
// fp32 1.0 -> dword 0x3F800000 ; two bf16 1.0 -> dword 0x3F803F80
__global__ void detect_kernel(const void* mask, int* flag) {
    unsigned u = *(const unsigned*)mask;
    *flag = (u == 0x3F803F80u) ? 1 : 0;
}

// ---------- GEMM: C = X @ W^T  (M=4096, N=K=1024) ----------
// mode 0: scatter C into (B,H,L,64) layout for attention; mode 1: plain row-major
#define TS 32
template<bool XBF, bool WBF>
__global__ __launch_bounds__(1024)
void gemm_xwT(const void* __restrict__ X, const void* __restrict__ W,
              float* __restrict__ C, const int* __restrict__ flag,
              int bfexp, int mode) {
    if (((*flag) != 0) != (bfexp != 0)) return;
    __shared__ float Xs[TS][TS + 1];
    __shared__ float Ws[TS][TS + 1];
    const int tx = threadIdx.x, ty = threadIdx.y;
    const int row = blockIdx.y * TS + ty;
    const int colBase = blockIdx.x * TS;
    const int col = colBase + tx;
    float acc = 0.f;
    for (int k0 = 0; k0 < DMODEL; k0 += TS) {
        Xs[ty][tx] = ldin<XBF>(X, (size_t)row * DMODEL + k0 + tx);
        Ws[ty][tx] = ldin<WBF>(W, (size_t)(colBase + ty) * DMODEL + k0 + tx);
        __syncthreads();
        #pragma unroll
        for (int kk = 0; kk < TS; ++kk)
            acc += Xs[ty][kk] * Ws[tx][kk];
        __syncthreads();
    }
    if (mode == 0) {
        const int b = row >> 11, l = row & (L_SEQ - 1);
        const int h = col >> 6,  d = col & (DHEAD - 1);
        C[(((size_t)b * HEADS + h) * L_SEQ + l) * DHEAD + d] = acc;
    } else {
        C[(size_t)row * DMODEL + col] = acc;
    }
}

// ---------- attention: one block per (b,h,q) ----------
template<bool BF>
__global__ __launch_bounds__(256)
void attn_kernel(const float* __restrict__ Qb, const float* __restrict__ Kb,
                 const float* __restrict__ Vb, const void* __restrict__ mask,
                 const void* __restrict__ sfp, const void* __restrict__ taup,
                 const int* __restrict__ wszp, float* __restrict__ Ob,
                 void* __restrict__ out, const int* __restrict__ flag, int bfexp) {
    if (((*flag) != 0) != (bfexp != 0)) return;
    const int q  = blockIdx.x;
    const int bh = blockIdx.y;          // b*16 + h
    const int b  = bh >> 4;
    const int t  = threadIdx.x;
    __shared__ float qv[DHEAD];
    __shared__ float sc[L_SEQ];
    __shared__ float red[256];
    __shared__ float part[4][DHEAD];
    const float sfv  = ldin<BF>(sfp, 0);
    const float tauv = ldin<BF>(taup, 0);
    const int   W2   = (*wszp) >> 1;
    const float maskq = ldin<BF>(mask, (size_t)b * L_SEQ + q);
    if (t < DHEAD) qv[t] = Qb[((size_t)bh * L_SEQ + q) * DHEAD + t];
    __syncthreads();

    int jlo, jhi; bool use_qk;
    if (maskq != 0.0f) {
        jlo = q - W2; if (jlo < 0) jlo = 0;
        jhi = q + W2; if (jhi > L_SEQ - 1) jhi = L_SEQ - 1;
        use_qk = true;
    } else {
        // whole query row masked: scores = NEG - bias everywhere -> softmax(-bias)
        jlo = 0; jhi = L_SEQ - 1; use_qk = false;
    }

    float lmax = -1e30f;
    for (int j = jlo + t; j <= jhi; j += 256) {
        const float rel  = (float)(q - j);
        const float bias = expf(-fabsf(rel / sfv) / tauv);
        float s;
        if (use_qk) {
            const float* kr = Kb + ((size_t)bh * L_SEQ + j) * DHEAD;
            float dot = 0.f;
            #pragma unroll
            for (int d = 0; d < DHEAD; ++d) dot += qv[d] * kr[d];
            s = dot * 0.125f - bias;
        } else {
            s = -bias;
        }
        sc[j] = s;
        lmax = fmaxf(lmax, s);
    }
    red[t] = lmax; __syncthreads();
    for (int o = 128; o > 0; o >>= 1) { if (t < o) red[t] = fmaxf(red[t], red[t + o]); __syncthreads(); }
    const float M = red[0];
    __syncthreads();

    float lsum = 0.f;
    for (int j = jlo + t; j <= jhi; j += 256) {
        const float p = expf(sc[j] - M);
        sc[j] = p; lsum += p;
    }
    red[t] = lsum; __syncthreads();
    for (int o = 128; o > 0; o >>= 1) { if (t < o) red[t] += red[t + o]; __syncthreads(); }
    const float inv = 1.0f / red[0];

    // write full attention row (zeros outside the window, matching fp32 underflow)
    const size_t abase = ATT_OFF + ((size_t)bh * L_SEQ + q) * L_SEQ;
    for (int c = t; c < L_SEQ; c += 256) {
        const float v = (c >= jlo && c <= jhi) ? sc[c] * inv : 0.0f;
        stout<BF>(out, abase + c, v);
    }

    // P @ V : 4 groups x 64 dims
    const int d = t & (DHEAD - 1), g = t >> 6;
    float acc = 0.f;
    for (int j = jlo + g; j <= jhi; j += 4)
        acc += sc[j] * Vb[((size_t)bh * L_SEQ + j) * DHEAD + d];
    part[g][d] = acc; __syncthreads();
    if (t < DHEAD) {
        const float o4 = (part[0][t] + part[1][t] + part[2][t] + part[3][t]) * inv;
        const int h = bh & 15;
        Ob[((size_t)b * L_SEQ + q) * DMODEL + h * DHEAD + t] = o4;
    }
}

// ---------- residual + LayerNorm ----------
template<bool BF>
__global__ __launch_bounds__(256)
void ln_kernel(const float* __restrict__ Pb, const void* __restrict__ qin,
               const void* __restrict__ lnw, const void* __restrict__ lnb,
               void* __restrict__ out, const int* __restrict__ flag, int bfexp) {
    if (((*flag) != 0) != (bfexp != 0)) return;
    const int row = blockIdx.x;
    const int t = threadIdx.x;
    __shared__ float xs[DMODEL];
    __shared__ float red[256];
    float s = 0.f;
    for (int i = t; i < DMODEL; i += 256) {
        const float v = Pb[(size_t)row * DMODEL + i] + ldin<BF>(qin, (size_t)row * DMODEL + i);
        xs[i] = v; s += v;
    }
    red[t] = s; __syncthreads();
    for (int o = 128; o > 0; o >>= 1) { if (t < o) red[t] += red[t + o]; __syncthreads(); }
    const float mu = red[0] * (1.0f / DMODEL);
    __syncthreads();
    float s2 = 0.f;
    for (int i = t; i < DMODEL; i += 256) { const float dv = xs[i] - mu; s2 += dv * dv; }
    red[t] = s2; __syncthreads();
    for (int o = 128; o > 0; o >>= 1) { if (t < o) red[t] += red[t + o]; __syncthreads(); }
    const float rstd = rsqrtf(red[0] * (1.0f / DMODEL) + 1e-6f);
    for (int i = t; i < DMODEL; i += 256) {
        const float y = (xs[i] - mu) * rstd * ldin<BF>(lnw, i) + ldin<BF>(lnb, i);
        stout<BF>(out, (size_t)row * DMODEL + i, y);
    }
}

extern "C" void kernel_launch(void* const* d_in, const int* in_sizes, int n_in,
                              void* d_out, int out_size, void* d_ws, size_t ws_size,
                              hipStream_t stream) {
    const void* q_in = d_in[0];
    const void* k_in = d_in[1];
    const void* v_in = d_in[2];
    const void* mask = d_in[3];
    const void* Wq   = d_in[4];
    const void* Wk   = d_in[5];
    const void* Wv   = d_in[6];
    const void* Wo   = d_in[7];
    const void* sf   = d_in[8];
    const void* tau  = d_in[9];
    const void* lnw  = d_in[10];
    const void* lnb  = d_in[11];
    const int*  wsz  = (const int*)d_in[12];
    (void)in_sizes; (void)n_in; (void)out_size; (void)ws_size;

    int*   flag = (int*)d_ws;
    float* A    = ((float*)d_ws) + 64;          // 256B header for flag
    float* Qb   = A;                            // 4096*1024 fp32
    float* Kb   = A + 4194304;
    float* Vb   = A + 8388608;
    float* Ob   = A + 12582912;                 // attention out (B,L,1024)
    float* Pb   = A;                            // Wo output reuses Q region (Q dead by then)

    detect_kernel<<<1, 1, 0, stream>>>(mask, flag);

    dim3 gb(TS, TS);
    dim3 gg(DMODEL / TS, ROWS / TS);            // (32, 128)

    // projections -> (B,H,L,64)
    gemm_xwT<false, false><<<gg, gb, 0, stream>>>(q_in, Wq, Qb, flag, 0, 0);
    gemm_xwT<true,  true ><<<gg, gb, 0, stream>>>(q_in, Wq, Qb, flag, 1, 0);
    gemm_xwT<false, false><<<gg, gb, 0, stream>>>(k_in, Wk, Kb, flag, 0, 0);
    gemm_xwT<true,  true ><<<gg, gb, 0, stream>>>(k_in, Wk, Kb, flag, 1, 0);
    gemm_xwT<false, false><<<gg, gb, 0, stream>>>(v_in, Wv, Vb, flag, 0, 0);
    gemm_xwT<true,  true ><<<gg, gb, 0, stream>>>(v_in, Wv, Vb, flag, 1, 0);

    // attention + full attention-matrix write + P@V
    dim3 ag(L_SEQ, BATCH * HEADS);
    attn_kernel<false><<<ag, 256, 0, stream>>>(Qb, Kb, Vb, mask, sf, tau, wsz, Ob, d_out, flag, 0);
    attn_kernel<true ><<<ag, 256, 0, stream>>>(Qb, Kb, Vb, mask, sf, tau, wsz, Ob, d_out, flag, 1);

    // output projection (X = Ob is fp32 workspace; only W dtype varies)
    gemm_xwT<false, false><<<gg, gb, 0, stream>>>(Ob, Wo, Pb, flag, 0, 1);
    gemm_xwT<false, true ><<<gg, gb, 0, stream>>>(Ob, Wo, Pb, flag, 1, 1);

    // residual + LayerNorm -> x
    ln_kernel<false><<<ROWS, 256, 0, stream>>>(Pb, q_in, lnw, lnb, d_out, flag, 0);
    ln_kernel<true ><<<ROWS, 256, 0, stream>>>(Pb, q_in, lnw, lnb, d_out, flag, 1);
}